// Round 7
// baseline (843.542 us; speedup 1.0000x reference)
//
#include <hip/hip_runtime.h>
#include <hip/hip_fp16.h>
#include <cstdint>
#include <cstddef>

// LSTM: B=32, T=1024, D=1024, H=128, gates 4H=512 (order i,f,g,o).
//   prep:     W_ih fp32->fp16, W_hh fp32->fp16, bsum = b_ih + b_hh
//   gemm_gx:  gx[32768][512] = x @ W_ih^T + bsum   (fp16 MFMA, fp32 acc)
//   lstm_rec: 32 blocks (1/batch) x 512 threads; thread t = 4*j + gate.
//     vs r5: weights PINNED in VGPRs (launch_bounds(512,1) + asm pin — r5's
//     VGPR=48 proved the compiler was re-loading W_hh from L2 every step),
//     gate exchange via DPP quad_perm (VALU) instead of ds_bpermute shfl,
//     h accumulated in a 64-step LDS ring and flushed coalesced (kills the
//     per-step divergent global store + its vmcnt wait on the serial chain),
//     gx register-prefetch distance 2, exp2f-based activations.
//   r6 fix: DPP ctrl must be a compile-time immediate -> template parameter.

typedef __attribute__((ext_vector_type(8))) _Float16 half8;
typedef __attribute__((ext_vector_type(4))) _Float16 half4;
typedef __attribute__((ext_vector_type(4))) float    f32x4;

#define BT    32768   // B*T
#define DD    1024
#define GG    512     // 4*H
#define HH    128
#define TT    1024
#define BB    32

// ---------------- prep: fp16 conversions + bias sum ----------------
__global__ void prep_kernel(const float* __restrict__ wih,
                            const float* __restrict__ whh,
                            const float* __restrict__ bih,
                            const float* __restrict__ bhh,
                            _Float16* __restrict__ wih_h,
                            __half*   __restrict__ whh_h,
                            float* __restrict__ bsum) {
    int i = blockIdx.x * 256 + threadIdx.x;   // grid covers 512*1024 exactly
    wih_h[i] = (_Float16)wih[i];
    if (i < GG * HH) whh_h[i] = __float2half(whh[i]);
    if (i < GG)      bsum[i] = bih[i] + bhh[i];
}

// ---------------- GEMM: gx = x @ W_ih^T + bsum (unchanged, verified) --------
#define BM 128
#define BN 128
#define BK 32
#define LDP 40   // LDS row pitch in halves (80B rows, 2-way bank alias = free)

__global__ __launch_bounds__(256)
void gemm_gx(const float* __restrict__ x, const _Float16* __restrict__ wih_h,
             const float* __restrict__ bsum, float* __restrict__ gx) {
    const int bid = blockIdx.x;
    const int m0 = (bid >> 2) * BM;
    const int n0 = (bid & 3) * BN;
    const int t  = threadIdx.x;
    const int lane = t & 63;
    const int w  = t >> 6;
    const int wr = w >> 1, wc = w & 1;
    const int lr = lane & 15;
    const int lk = lane >> 4;

    __shared__ __align__(16) _Float16 As[BM][LDP];
    __shared__ __align__(16) _Float16 Bs[BN][LDP];

    f32x4 acc[4][4] = {};

    for (int kt = 0; kt < DD; kt += BK) {
        #pragma unroll
        for (int pass = 0; pass < 4; ++pass) {
            int r = pass * 32 + (t >> 3);
            int c = (t & 7) * 4;
            float4 v = *(const float4*)(x + (size_t)(m0 + r) * DD + kt + c);
            half4 hv;
            hv[0] = (_Float16)v.x; hv[1] = (_Float16)v.y;
            hv[2] = (_Float16)v.z; hv[3] = (_Float16)v.w;
            *(half4*)&As[r][c] = hv;
        }
        #pragma unroll
        for (int pass = 0; pass < 2; ++pass) {
            int r = pass * 64 + (t >> 2);
            int c = (t & 3) * 8;
            float4 v = *(const float4*)(wih_h + (size_t)(n0 + r) * DD + kt + c);
            *(float4*)&Bs[r][c] = v;
        }
        __syncthreads();

        half8 af[4], bf[4];
        #pragma unroll
        for (int i = 0; i < 4; ++i)
            af[i] = *(const half8*)&As[wr * 64 + i * 16 + lr][lk * 8];
        #pragma unroll
        for (int j = 0; j < 4; ++j)
            bf[j] = *(const half8*)&Bs[wc * 64 + j * 16 + lr][lk * 8];

        #pragma unroll
        for (int i = 0; i < 4; ++i)
            #pragma unroll
            for (int j = 0; j < 4; ++j)
                acc[i][j] = __builtin_amdgcn_mfma_f32_16x16x32_f16(af[i], bf[j], acc[i][j], 0, 0, 0);
        __syncthreads();
    }

    #pragma unroll
    for (int j = 0; j < 4; ++j) {
        int n = n0 + wc * 64 + j * 16 + lr;
        float bn = bsum[n];
        #pragma unroll
        for (int i = 0; i < 4; ++i) {
            int mbase = m0 + wr * 64 + i * 16 + lk * 4;
            #pragma unroll
            for (int r = 0; r < 4; ++r)
                gx[(size_t)(mbase + r) * GG + n] = acc[i][j][r] + bn;
        }
    }
}

// ---------------- recurrence ----------------
// thread t: j = t>>2 (h index), gi = t&3 (0=i,1=f,2=g,3=o); gate row r = gi*128+j.

__device__ __forceinline__ __half2 u2h(uint32_t v) { return *(__half2*)&v; }

// DPP quad_perm lane swizzle (VALU; zero DS latency). ctrl must be immediate.
template <int CTRL>
__device__ __forceinline__ float dpp_qp(float x) {
    int i = __float_as_int(x);
    i = __builtin_amdgcn_update_dpp(0, i, CTRL, 0xF, 0xF, true);
    return __int_as_float(i);
}
#define QP_XOR1 0xB1   // [1,0,3,2]
#define QP_XOR2 0x4E   // [2,3,0,1]

#define LOG2E   1.4426950408889634f

__global__ __launch_bounds__(512, 1)
void lstm_rec(const float* __restrict__ gx, const __half* __restrict__ whh_h,
              float* __restrict__ out, float* __restrict__ hn, float* __restrict__ cn) {
    const int b  = blockIdx.x;
    const int t  = threadIdx.x;
    const int j  = t >> 2;
    const int gi = t & 3;
    const int r  = gi * HH + j;

    __shared__ __align__(16) __half hbuf[2][HH];    // double-buffered h (512 B)
    __shared__ __align__(16) float  oring[64][HH];  // 64-step output ring (32 KiB)

    // W_hh row r -> 64 dwords (fp16x2) pinned in VGPRs
    uint32_t wv[64];
    {
        const uint4* wp = (const uint4*)(whh_h + (size_t)r * HH);
        #pragma unroll
        for (int q = 0; q < 16; ++q) {
            uint4 u = wp[q];
            wv[4 * q + 0] = u.x; wv[4 * q + 1] = u.y;
            wv[4 * q + 2] = u.z; wv[4 * q + 3] = u.w;
        }
    }
    #pragma unroll
    for (int q = 0; q < 64; ++q) asm volatile("" : "+v"(wv[q]));  // pin in regs

    // branchless activation constants: gate g (gi==2) is tanh = 2*sigma(2x)-1
    // s = 1/(1 + exp2(pre * kneg)); a = k2*s + k3
    const float kneg = (gi == 2) ? -2.f * LOG2E : -LOG2E;
    const float k2   = (gi == 2) ?  2.f : 1.f;
    const float k3   = (gi == 2) ? -1.f : 0.f;

    if (t < HH) hbuf[0][t] = __float2half(0.f);
    __syncthreads();

    const float* gxp  = gx + (size_t)b * TT * GG + r;
    float*       outp = out + (size_t)b * TT * HH;

    float c = 0.f, hval = 0.f;
    float p0 = gxp[0];
    float p1 = gxp[GG];

    for (int step = 0; step < TT; ++step) {
        // prefetch step+2 (register, distance 2 covers ~900cy HBM latency)
        int sp = step + 2; if (sp > TT - 1) sp = TT - 1;
        float p2 = gxp[(size_t)sp * GG];

        // dot(w_row, h_prev): 16x ds_read_b128 broadcast + 64x v_pk_fma_f16
        const uint4* hp = (const uint4*)hbuf[step & 1];
        __half2 acc[8];
        #pragma unroll
        for (int k = 0; k < 8; ++k) acc[k] = __float2half2_rn(0.f);
        #pragma unroll
        for (int q = 0; q < 16; ++q) {
            uint4 hv4 = hp[q];
            const int ab = (q & 1) * 4;
            acc[ab + 0] = __hfma2(u2h(wv[4 * q + 0]), u2h(hv4.x), acc[ab + 0]);
            acc[ab + 1] = __hfma2(u2h(wv[4 * q + 1]), u2h(hv4.y), acc[ab + 1]);
            acc[ab + 2] = __hfma2(u2h(wv[4 * q + 2]), u2h(hv4.z), acc[ab + 2]);
            acc[ab + 3] = __hfma2(u2h(wv[4 * q + 3]), u2h(hv4.w), acc[ab + 3]);
        }
        acc[0] = __hadd2(acc[0], acc[4]); acc[1] = __hadd2(acc[1], acc[5]);
        acc[2] = __hadd2(acc[2], acc[6]); acc[3] = __hadd2(acc[3], acc[7]);
        acc[0] = __hadd2(acc[0], acc[2]); acc[1] = __hadd2(acc[1], acc[3]);
        acc[0] = __hadd2(acc[0], acc[1]);
        float pre = p0 + __low2float(acc[0]) + __high2float(acc[0]);

        // activation (branchless, exp2-based)
        float s = __builtin_amdgcn_rcpf(1.f + exp2f(pre * kneg));
        float a = fmaf(k2, s, k3);

        // in-quad gate exchange via DPP: lane gi==0 gets (a=i, x1=f, x2=g, x3=o)
        float x1 = dpp_qp<QP_XOR1>(a);
        float x2 = dpp_qp<QP_XOR2>(a);
        float x3 = dpp_qp<QP_XOR2>(x1);

        if (gi == 0) {
            c = fmaf(x1, c, a * x2);
            float th = fmaf(2.f, __builtin_amdgcn_rcpf(1.f + exp2f(-2.f * LOG2E * c)), -1.f);
            hval = x3 * th;
            hbuf[(step + 1) & 1][j] = __float2half(hval);
            oring[step & 63][j] = hval;       // out buffered in LDS, not global
        }

        // one barrier per step: LDS-only drain (no vmcnt on the serial chain)
        __builtin_amdgcn_sched_barrier(0);
        asm volatile("s_waitcnt lgkmcnt(0)" ::: "memory");
        __builtin_amdgcn_s_barrier();
        __builtin_amdgcn_sched_barrier(0);

        // coalesced flush of 64 steps of h (all 512 threads, float4)
        if ((step & 63) == 63) {
            float4*       dst = (float4*)(outp + (size_t)(step - 63) * HH);
            const float4* src = (const float4*)&oring[0][0];
            #pragma unroll
            for (int k = 0; k < 4; ++k)
                dst[t + k * 512] = src[t + k * 512];
            __syncthreads();   // ring-reuse guard (once per 64 steps)
        }

        p0 = p1; p1 = p2;
    }

    if (gi == 0) {
        hn[b * HH + j] = hval;
        cn[b * HH + j] = c;
    }
}

// ---------------- launch ----------------
extern "C" void kernel_launch(void* const* d_in, const int* in_sizes, int n_in,
                              void* d_out, int out_size, void* d_ws, size_t ws_size,
                              hipStream_t stream) {
    const float* x   = (const float*)d_in[0];
    const float* wih = (const float*)d_in[1];
    const float* whh = (const float*)d_in[2];
    const float* bih = (const float*)d_in[3];
    const float* bhh = (const float*)d_in[4];
    float* out = (float*)d_out;

    // ws layout: [W_ih fp16 1MB][W_hh fp16 128KB][bsum 2KB pad->4KB][gx fp32 64MB]
    char* ws = (char*)d_ws;
    _Float16* wih_h = (_Float16*)ws;
    __half*   whh_h = (__half*)(ws + (size_t)(1 << 20));
    float*    bsum  = (float*)(ws + (size_t)(1 << 20) + (128 << 10));
    float*    gx    = (float*)(ws + (size_t)(1 << 20) + (128 << 10) + 4096);

    prep_kernel<<<(GG * DD) / 256, 256, 0, stream>>>(wih, whh, bih, bhh, wih_h, whh_h, bsum);
    gemm_gx<<<(BT / BM) * (GG / BN), 256, 0, stream>>>(x, wih_h, bsum, gx);

    float* hn = out + (size_t)BB * TT * HH;
    float* cn = hn + BB * HH;
    lstm_rec<<<BB, 512, 0, stream>>>(gx, whh_h, out, hn, cn);
}

// Round 8
// 829.601 us; speedup vs baseline: 1.0168x; 1.0168x over previous
//
#include <hip/hip_runtime.h>
#include <hip/hip_fp16.h>
#include <cstdint>
#include <cstddef>

// LSTM: B=32, T=1024, D=1024, H=128, gates 4H=512 (order i,f,g,o).
//   prep:     W_ih fp32->fp16, W_hh fp32->fp16, bsum = b_ih + b_hh
//   gemm_gx:  gx[32768][512] = x @ W_ih^T + bsum   (fp16 MFMA, fp32 acc)
//   lstm_rec: 32 blocks (1/batch) x 512 threads; thread t = 4*j + gate.
//   r7 lesson: `for(q) asm("+v"(wv[q]))` = runtime index at SROA time ->
//   whole array demoted to scratch (VGPR=56, +95us). Fix: 64 *named* scalar
//   weights via macros, per-name asm pin. No register arrays anywhere.

typedef __attribute__((ext_vector_type(8))) _Float16 half8;
typedef __attribute__((ext_vector_type(4))) _Float16 half4;
typedef __attribute__((ext_vector_type(4))) float    f32x4;

#define BT    32768   // B*T
#define DD    1024
#define GG    512     // 4*H
#define HH    128
#define TT    1024
#define BB    32

// ---------------- prep: fp16 conversions + bias sum ----------------
__global__ void prep_kernel(const float* __restrict__ wih,
                            const float* __restrict__ whh,
                            const float* __restrict__ bih,
                            const float* __restrict__ bhh,
                            _Float16* __restrict__ wih_h,
                            __half*   __restrict__ whh_h,
                            float* __restrict__ bsum) {
    int i = blockIdx.x * 256 + threadIdx.x;   // grid covers 512*1024 exactly
    wih_h[i] = (_Float16)wih[i];
    if (i < GG * HH) whh_h[i] = __float2half(whh[i]);
    if (i < GG)      bsum[i] = bih[i] + bhh[i];
}

// ---------------- GEMM: gx = x @ W_ih^T + bsum (unchanged, verified) --------
#define BM 128
#define BN 128
#define BK 32
#define LDP 40   // LDS row pitch in halves (80B rows, 2-way bank alias = free)

__global__ __launch_bounds__(256)
void gemm_gx(const float* __restrict__ x, const _Float16* __restrict__ wih_h,
             const float* __restrict__ bsum, float* __restrict__ gx) {
    const int bid = blockIdx.x;
    const int m0 = (bid >> 2) * BM;
    const int n0 = (bid & 3) * BN;
    const int t  = threadIdx.x;
    const int lane = t & 63;
    const int w  = t >> 6;
    const int wr = w >> 1, wc = w & 1;
    const int lr = lane & 15;
    const int lk = lane >> 4;

    __shared__ __align__(16) _Float16 As[BM][LDP];
    __shared__ __align__(16) _Float16 Bs[BN][LDP];

    f32x4 acc[4][4] = {};

    for (int kt = 0; kt < DD; kt += BK) {
        #pragma unroll
        for (int pass = 0; pass < 4; ++pass) {
            int r = pass * 32 + (t >> 3);
            int c = (t & 7) * 4;
            float4 v = *(const float4*)(x + (size_t)(m0 + r) * DD + kt + c);
            half4 hv;
            hv[0] = (_Float16)v.x; hv[1] = (_Float16)v.y;
            hv[2] = (_Float16)v.z; hv[3] = (_Float16)v.w;
            *(half4*)&As[r][c] = hv;
        }
        #pragma unroll
        for (int pass = 0; pass < 2; ++pass) {
            int r = pass * 64 + (t >> 2);
            int c = (t & 3) * 8;
            float4 v = *(const float4*)(wih_h + (size_t)(n0 + r) * DD + kt + c);
            *(float4*)&Bs[r][c] = v;
        }
        __syncthreads();

        half8 af[4], bf[4];
        #pragma unroll
        for (int i = 0; i < 4; ++i)
            af[i] = *(const half8*)&As[wr * 64 + i * 16 + lr][lk * 8];
        #pragma unroll
        for (int j = 0; j < 4; ++j)
            bf[j] = *(const half8*)&Bs[wc * 64 + j * 16 + lr][lk * 8];

        #pragma unroll
        for (int i = 0; i < 4; ++i)
            #pragma unroll
            for (int j = 0; j < 4; ++j)
                acc[i][j] = __builtin_amdgcn_mfma_f32_16x16x32_f16(af[i], bf[j], acc[i][j], 0, 0, 0);
        __syncthreads();
    }

    #pragma unroll
    for (int j = 0; j < 4; ++j) {
        int n = n0 + wc * 64 + j * 16 + lr;
        float bn = bsum[n];
        #pragma unroll
        for (int i = 0; i < 4; ++i) {
            int mbase = m0 + wr * 64 + i * 16 + lk * 4;
            #pragma unroll
            for (int r = 0; r < 4; ++r)
                gx[(size_t)(mbase + r) * GG + n] = acc[i][j][r] + bn;
        }
    }
}

// ---------------- recurrence ----------------
// thread t: j = t>>2 (h index), gi = t&3 (0=i,1=f,2=g,3=o); gate row r = gi*128+j.

__device__ __forceinline__ __half2 u2h(uint32_t v) { return *(__half2*)&v; }

// DPP quad_perm lane swizzle (VALU; zero DS latency). ctrl must be immediate.
template <int CTRL>
__device__ __forceinline__ float dpp_qp(float x) {
    int i = __float_as_int(x);
    i = __builtin_amdgcn_update_dpp(0, i, CTRL, 0xF, 0xF, true);
    return __int_as_float(i);
}
#define QP_XOR1 0xB1   // [1,0,3,2]
#define QP_XOR2 0x4E   // [2,3,0,1]

#define LOG2E   1.4426950408889634f

// ---- 64 named weight dwords: load, pin, use — no arrays, no dynamic index ----
#define WDECL(Q)  uint32_t w##Q##x, w##Q##y, w##Q##z, w##Q##w;
#define WLOAD(Q)  { uint4 u_ = wp[Q]; w##Q##x = u_.x; w##Q##y = u_.y; \
                    w##Q##z = u_.z; w##Q##w = u_.w; }
#define WPIN(Q)   asm volatile("" : "+v"(w##Q##x), "+v"(w##Q##y), \
                                    "+v"(w##Q##z), "+v"(w##Q##w));
#define DOTE(Q)   { uint4 hv_ = hp[Q]; \
    a0 = __hfma2(u2h(w##Q##x), u2h(hv_.x), a0); \
    a1 = __hfma2(u2h(w##Q##y), u2h(hv_.y), a1); \
    a2 = __hfma2(u2h(w##Q##z), u2h(hv_.z), a2); \
    a3 = __hfma2(u2h(w##Q##w), u2h(hv_.w), a3); }
#define DOTO(Q)   { uint4 hv_ = hp[Q]; \
    a4 = __hfma2(u2h(w##Q##x), u2h(hv_.x), a4); \
    a5 = __hfma2(u2h(w##Q##y), u2h(hv_.y), a5); \
    a6 = __hfma2(u2h(w##Q##z), u2h(hv_.z), a6); \
    a7 = __hfma2(u2h(w##Q##w), u2h(hv_.w), a7); }
#define W16(F) F(0) F(1) F(2) F(3) F(4) F(5) F(6) F(7) \
               F(8) F(9) F(10) F(11) F(12) F(13) F(14) F(15)

__global__ __launch_bounds__(512, 2)
void lstm_rec(const float* __restrict__ gx, const __half* __restrict__ whh_h,
              float* __restrict__ out, float* __restrict__ hn, float* __restrict__ cn) {
    const int b  = blockIdx.x;
    const int t  = threadIdx.x;
    const int j  = t >> 2;
    const int gi = t & 3;
    const int r  = gi * HH + j;

    __shared__ __align__(16) __half hbuf[2][HH];    // double-buffered h (512 B)
    __shared__ __align__(16) float  oring[64][HH];  // 64-step output ring (32 KiB)

    // W_hh row r -> 64 named dwords (fp16x2), pinned in VGPRs
    const uint4* wp = (const uint4*)(whh_h + (size_t)r * HH);
    W16(WDECL)
    W16(WLOAD)
    W16(WPIN)

    // branchless activation constants: gate g (gi==2) is tanh = 2*sigma(2x)-1
    // s = 1/(1 + exp2(pre * kneg)); a = k2*s + k3
    const float kneg = (gi == 2) ? -2.f * LOG2E : -LOG2E;
    const float k2   = (gi == 2) ?  2.f : 1.f;
    const float k3   = (gi == 2) ? -1.f : 0.f;

    if (t < HH) hbuf[0][t] = __float2half(0.f);
    __syncthreads();

    const float* gxp  = gx + (size_t)b * TT * GG + r;
    float*       outp = out + (size_t)b * TT * HH;

    float c = 0.f, hval = 0.f;
    float p0 = gxp[0];
    float p1 = gxp[GG];

    for (int step = 0; step < TT; ++step) {
        // prefetch step+2 (register; distance 2 covers HBM/L2 latency)
        int sp = step + 2; if (sp > TT - 1) sp = TT - 1;
        float p2 = gxp[(size_t)sp * GG];

        // dot(w_row, h_prev): 16x ds_read_b128 broadcast + 64x v_pk_fma_f16
        const uint4* hp = (const uint4*)hbuf[step & 1];
        __half2 a0, a1, a2, a3, a4, a5, a6, a7;
        a0 = a1 = a2 = a3 = a4 = a5 = a6 = a7 = __float2half2_rn(0.f);
        DOTE(0)  DOTO(1)  DOTE(2)  DOTO(3)
        DOTE(4)  DOTO(5)  DOTE(6)  DOTO(7)
        DOTE(8)  DOTO(9)  DOTE(10) DOTO(11)
        DOTE(12) DOTO(13) DOTE(14) DOTO(15)
        a0 = __hadd2(a0, a4); a1 = __hadd2(a1, a5);
        a2 = __hadd2(a2, a6); a3 = __hadd2(a3, a7);
        a0 = __hadd2(a0, a2); a1 = __hadd2(a1, a3);
        a0 = __hadd2(a0, a1);
        float pre = p0 + __low2float(a0) + __high2float(a0);

        // activation (branchless, exp2-based)
        float s = __builtin_amdgcn_rcpf(1.f + exp2f(pre * kneg));
        float a = fmaf(k2, s, k3);

        // in-quad gate exchange via DPP: lane gi==0 gets (a=i, x1=f, x2=g, x3=o)
        float x1 = dpp_qp<QP_XOR1>(a);
        float x2 = dpp_qp<QP_XOR2>(a);
        float x3 = dpp_qp<QP_XOR2>(x1);

        if (gi == 0) {
            c = fmaf(x1, c, a * x2);
            float th = fmaf(2.f, __builtin_amdgcn_rcpf(1.f + exp2f(-2.f * LOG2E * c)), -1.f);
            hval = x3 * th;
            hbuf[(step + 1) & 1][j] = __float2half(hval);
            oring[step & 63][j] = hval;       // out buffered in LDS, not global
        }

        // one barrier per step: LDS-only drain (no vmcnt on the serial chain)
        __builtin_amdgcn_sched_barrier(0);
        asm volatile("s_waitcnt lgkmcnt(0)" ::: "memory");
        __builtin_amdgcn_s_barrier();
        __builtin_amdgcn_sched_barrier(0);

        // coalesced flush of 64 steps of h (all 512 threads, float4)
        if ((step & 63) == 63) {
            float4*       dst = (float4*)(outp + (size_t)(step - 63) * HH);
            const float4* src = (const float4*)&oring[0][0];
            #pragma unroll
            for (int k = 0; k < 4; ++k)
                dst[t + k * 512] = src[t + k * 512];
            __syncthreads();   // ring-reuse guard (once per 64 steps)
        }

        p0 = p1; p1 = p2;
    }

    if (gi == 0) {
        hn[b * HH + j] = hval;
        cn[b * HH + j] = c;
    }
}

// ---------------- launch ----------------
extern "C" void kernel_launch(void* const* d_in, const int* in_sizes, int n_in,
                              void* d_out, int out_size, void* d_ws, size_t ws_size,
                              hipStream_t stream) {
    const float* x   = (const float*)d_in[0];
    const float* wih = (const float*)d_in[1];
    const float* whh = (const float*)d_in[2];
    const float* bih = (const float*)d_in[3];
    const float* bhh = (const float*)d_in[4];
    float* out = (float*)d_out;

    // ws layout: [W_ih fp16 1MB][W_hh fp16 128KB][bsum 2KB pad->4KB][gx fp32 64MB]
    char* ws = (char*)d_ws;
    _Float16* wih_h = (_Float16*)ws;
    __half*   whh_h = (__half*)(ws + (size_t)(1 << 20));
    float*    bsum  = (float*)(ws + (size_t)(1 << 20) + (128 << 10));
    float*    gx    = (float*)(ws + (size_t)(1 << 20) + (128 << 10) + 4096);

    prep_kernel<<<(GG * DD) / 256, 256, 0, stream>>>(wih, whh, bih, bhh, wih_h, whh_h, bsum);
    gemm_gx<<<(BT / BM) * (GG / BN), 256, 0, stream>>>(x, wih_h, bsum, gx);

    float* hn = out + (size_t)BB * TT * HH;
    float* cn = hn + BB * HH;
    lstm_rec<<<BB, 512, 0, stream>>>(gx, whh_h, out, hn, cn);
}

// Round 9
// 804.087 us; speedup vs baseline: 1.0491x; 1.0317x over previous
//
#include <hip/hip_runtime.h>
#include <hip/hip_fp16.h>
#include <cstdint>
#include <cstddef>

// LSTM: B=32, T=1024, D=1024, H=128, gates 4H=512 (order i,f,g,o).
//   prep:     W_ih fp32->fp16, W_hh fp32->fp16, bsum = b_ih + b_hh
//   gemm_gx:  gx[32768][512] = x @ W_ih^T + bsum   (fp16 MFMA, fp32 acc)
//   lstm_rec: 32 blocks (1/batch) x 512 threads; thread t = 4*j + gate.
//   r7/r8 lesson: __launch_bounds__ min-waves only CAPS VGPRs; the backend's
//   occupancy heuristic still sinks invariant weight loads into the loop
//   (VGPR=52/56, reloads from L2 every step). Fix: amdgpu_waves_per_eu(2,2)
//   pins the occupancy TARGET to what we actually run (8 waves = 2/EU),
//   removing the allocator's incentive to shed the 64 weight dwords.

typedef __attribute__((ext_vector_type(8))) _Float16 half8;
typedef __attribute__((ext_vector_type(4))) _Float16 half4;
typedef __attribute__((ext_vector_type(4))) float    f32x4;

#define BT    32768   // B*T
#define DD    1024
#define GG    512     // 4*H
#define HH    128
#define TT    1024
#define BB    32

// ---------------- prep: fp16 conversions + bias sum ----------------
__global__ void prep_kernel(const float* __restrict__ wih,
                            const float* __restrict__ whh,
                            const float* __restrict__ bih,
                            const float* __restrict__ bhh,
                            _Float16* __restrict__ wih_h,
                            __half*   __restrict__ whh_h,
                            float* __restrict__ bsum) {
    int i = blockIdx.x * 256 + threadIdx.x;   // grid covers 512*1024 exactly
    wih_h[i] = (_Float16)wih[i];
    if (i < GG * HH) whh_h[i] = __float2half(whh[i]);
    if (i < GG)      bsum[i] = bih[i] + bhh[i];
}

// ---------------- GEMM: gx = x @ W_ih^T + bsum (unchanged, verified) --------
#define BM 128
#define BN 128
#define BK 32
#define LDP 40   // LDS row pitch in halves (80B rows, 2-way bank alias = free)

__global__ __launch_bounds__(256)
void gemm_gx(const float* __restrict__ x, const _Float16* __restrict__ wih_h,
             const float* __restrict__ bsum, float* __restrict__ gx) {
    const int bid = blockIdx.x;
    const int m0 = (bid >> 2) * BM;
    const int n0 = (bid & 3) * BN;
    const int t  = threadIdx.x;
    const int lane = t & 63;
    const int w  = t >> 6;
    const int wr = w >> 1, wc = w & 1;
    const int lr = lane & 15;
    const int lk = lane >> 4;

    __shared__ __align__(16) _Float16 As[BM][LDP];
    __shared__ __align__(16) _Float16 Bs[BN][LDP];

    f32x4 acc[4][4] = {};

    for (int kt = 0; kt < DD; kt += BK) {
        #pragma unroll
        for (int pass = 0; pass < 4; ++pass) {
            int r = pass * 32 + (t >> 3);
            int c = (t & 7) * 4;
            float4 v = *(const float4*)(x + (size_t)(m0 + r) * DD + kt + c);
            half4 hv;
            hv[0] = (_Float16)v.x; hv[1] = (_Float16)v.y;
            hv[2] = (_Float16)v.z; hv[3] = (_Float16)v.w;
            *(half4*)&As[r][c] = hv;
        }
        #pragma unroll
        for (int pass = 0; pass < 2; ++pass) {
            int r = pass * 64 + (t >> 2);
            int c = (t & 3) * 8;
            float4 v = *(const float4*)(wih_h + (size_t)(n0 + r) * DD + kt + c);
            *(float4*)&Bs[r][c] = v;
        }
        __syncthreads();

        half8 af[4], bf[4];
        #pragma unroll
        for (int i = 0; i < 4; ++i)
            af[i] = *(const half8*)&As[wr * 64 + i * 16 + lr][lk * 8];
        #pragma unroll
        for (int j = 0; j < 4; ++j)
            bf[j] = *(const half8*)&Bs[wc * 64 + j * 16 + lr][lk * 8];

        #pragma unroll
        for (int i = 0; i < 4; ++i)
            #pragma unroll
            for (int j = 0; j < 4; ++j)
                acc[i][j] = __builtin_amdgcn_mfma_f32_16x16x32_f16(af[i], bf[j], acc[i][j], 0, 0, 0);
        __syncthreads();
    }

    #pragma unroll
    for (int j = 0; j < 4; ++j) {
        int n = n0 + wc * 64 + j * 16 + lr;
        float bn = bsum[n];
        #pragma unroll
        for (int i = 0; i < 4; ++i) {
            int mbase = m0 + wr * 64 + i * 16 + lk * 4;
            #pragma unroll
            for (int r = 0; r < 4; ++r)
                gx[(size_t)(mbase + r) * GG + n] = acc[i][j][r] + bn;
        }
    }
}

// ---------------- recurrence ----------------
// thread t: j = t>>2 (h index), gi = t&3 (0=i,1=f,2=g,3=o); gate row r = gi*128+j.

__device__ __forceinline__ __half2 u2h(uint32_t v) { return *(__half2*)&v; }

// DPP quad_perm lane swizzle (VALU; zero DS latency). ctrl must be immediate.
template <int CTRL>
__device__ __forceinline__ float dpp_qp(float x) {
    int i = __float_as_int(x);
    i = __builtin_amdgcn_update_dpp(0, i, CTRL, 0xF, 0xF, true);
    return __int_as_float(i);
}
#define QP_XOR1 0xB1   // [1,0,3,2]
#define QP_XOR2 0x4E   // [2,3,0,1]

#define LOG2E   1.4426950408889634f

// ---- 64 named weight dwords: load, pin, use — no arrays, no dynamic index ----
#define WDECL(Q)  uint32_t w##Q##x, w##Q##y, w##Q##z, w##Q##w;
#define WLOAD(Q)  { uint4 u_ = wp[Q]; w##Q##x = u_.x; w##Q##y = u_.y; \
                    w##Q##z = u_.z; w##Q##w = u_.w; }
#define WPIN(Q)   asm volatile("" : "+v"(w##Q##x), "+v"(w##Q##y), \
                                    "+v"(w##Q##z), "+v"(w##Q##w));
#define DOTE(Q)   { uint4 hv_ = hp[Q]; \
    a0 = __hfma2(u2h(w##Q##x), u2h(hv_.x), a0); \
    a1 = __hfma2(u2h(w##Q##y), u2h(hv_.y), a1); \
    a2 = __hfma2(u2h(w##Q##z), u2h(hv_.z), a2); \
    a3 = __hfma2(u2h(w##Q##w), u2h(hv_.w), a3); }
#define DOTO(Q)   { uint4 hv_ = hp[Q]; \
    a4 = __hfma2(u2h(w##Q##x), u2h(hv_.x), a4); \
    a5 = __hfma2(u2h(w##Q##y), u2h(hv_.y), a5); \
    a6 = __hfma2(u2h(w##Q##z), u2h(hv_.z), a6); \
    a7 = __hfma2(u2h(w##Q##w), u2h(hv_.w), a7); }
#define W16(F) F(0) F(1) F(2) F(3) F(4) F(5) F(6) F(7) \
               F(8) F(9) F(10) F(11) F(12) F(13) F(14) F(15)

__global__ __launch_bounds__(512)
__attribute__((amdgpu_waves_per_eu(2, 2)))
void lstm_rec(const float* __restrict__ gx, const __half* __restrict__ whh_h,
              float* __restrict__ out, float* __restrict__ hn, float* __restrict__ cn) {
    const int b  = blockIdx.x;
    const int t  = threadIdx.x;
    const int j  = t >> 2;
    const int gi = t & 3;
    const int r  = gi * HH + j;

    __shared__ __align__(16) __half hbuf[2][HH];    // double-buffered h (512 B)
    __shared__ __align__(16) float  oring[64][HH];  // 64-step output ring (32 KiB)

    // W_hh row r -> 64 named dwords (fp16x2), pinned in VGPRs
    const uint4* wp = (const uint4*)(whh_h + (size_t)r * HH);
    W16(WDECL)
    W16(WLOAD)
    W16(WPIN)

    // branchless activation constants: gate g (gi==2) is tanh = 2*sigma(2x)-1
    // s = 1/(1 + exp2(pre * kneg)); a = k2*s + k3
    const float kneg = (gi == 2) ? -2.f * LOG2E : -LOG2E;
    const float k2   = (gi == 2) ?  2.f : 1.f;
    const float k3   = (gi == 2) ? -1.f : 0.f;

    if (t < HH) hbuf[0][t] = __float2half(0.f);
    __syncthreads();

    const float* gxp  = gx + (size_t)b * TT * GG + r;
    float*       outp = out + (size_t)b * TT * HH;

    float c = 0.f, hval = 0.f;
    float p0 = gxp[0];
    float p1 = gxp[GG];

    for (int step = 0; step < TT; ++step) {
        // prefetch step+2 (register; distance 2 covers HBM/L2 latency)
        int sp = step + 2; if (sp > TT - 1) sp = TT - 1;
        float p2 = gxp[(size_t)sp * GG];

        // dot(w_row, h_prev): 16x ds_read_b128 broadcast + 64x v_pk_fma_f16
        const uint4* hp = (const uint4*)hbuf[step & 1];
        __half2 a0, a1, a2, a3, a4, a5, a6, a7;
        a0 = a1 = a2 = a3 = a4 = a5 = a6 = a7 = __float2half2_rn(0.f);
        DOTE(0)  DOTO(1)  DOTE(2)  DOTO(3)
        DOTE(4)  DOTO(5)  DOTE(6)  DOTO(7)
        DOTE(8)  DOTO(9)  DOTE(10) DOTO(11)
        DOTE(12) DOTO(13) DOTE(14) DOTO(15)
        a0 = __hadd2(a0, a4); a1 = __hadd2(a1, a5);
        a2 = __hadd2(a2, a6); a3 = __hadd2(a3, a7);
        a0 = __hadd2(a0, a2); a1 = __hadd2(a1, a3);
        a0 = __hadd2(a0, a1);
        float pre = p0 + __low2float(a0) + __high2float(a0);

        // activation (branchless; bare v_exp_f32 via builtin)
        float s = __builtin_amdgcn_rcpf(1.f + __builtin_amdgcn_exp2f(pre * kneg));
        float a = fmaf(k2, s, k3);

        // in-quad gate exchange via DPP: lane gi==0 gets (a=i, x1=f, x2=g, x3=o)
        float x1 = dpp_qp<QP_XOR1>(a);
        float x2 = dpp_qp<QP_XOR2>(a);
        float x3 = dpp_qp<QP_XOR2>(x1);

        if (gi == 0) {
            c = fmaf(x1, c, a * x2);
            float th = fmaf(2.f, __builtin_amdgcn_rcpf(
                          1.f + __builtin_amdgcn_exp2f(-2.f * LOG2E * c)), -1.f);
            hval = x3 * th;
            hbuf[(step + 1) & 1][j] = __float2half(hval);
            oring[step & 63][j] = hval;       // out buffered in LDS, not global
        }

        // one barrier per step: LDS-only drain (no vmcnt on the serial chain)
        __builtin_amdgcn_sched_barrier(0);
        asm volatile("s_waitcnt lgkmcnt(0)" ::: "memory");
        __builtin_amdgcn_s_barrier();
        __builtin_amdgcn_sched_barrier(0);

        // coalesced flush of 64 steps of h (all 512 threads, float4)
        if ((step & 63) == 63) {
            float4*       dst = (float4*)(outp + (size_t)(step - 63) * HH);
            const float4* src = (const float4*)&oring[0][0];
            #pragma unroll
            for (int k = 0; k < 4; ++k)
                dst[t + k * 512] = src[t + k * 512];
            __syncthreads();   // ring-reuse guard (once per 64 steps)
        }

        p0 = p1; p1 = p2;
    }

    if (gi == 0) {
        hn[b * HH + j] = hval;
        cn[b * HH + j] = c;
    }
}

// ---------------- launch ----------------
extern "C" void kernel_launch(void* const* d_in, const int* in_sizes, int n_in,
                              void* d_out, int out_size, void* d_ws, size_t ws_size,
                              hipStream_t stream) {
    const float* x   = (const float*)d_in[0];
    const float* wih = (const float*)d_in[1];
    const float* whh = (const float*)d_in[2];
    const float* bih = (const float*)d_in[3];
    const float* bhh = (const float*)d_in[4];
    float* out = (float*)d_out;

    // ws layout: [W_ih fp16 1MB][W_hh fp16 128KB][bsum 2KB pad->4KB][gx fp32 64MB]
    char* ws = (char*)d_ws;
    _Float16* wih_h = (_Float16*)ws;
    __half*   whh_h = (__half*)(ws + (size_t)(1 << 20));
    float*    bsum  = (float*)(ws + (size_t)(1 << 20) + (128 << 10));
    float*    gx    = (float*)(ws + (size_t)(1 << 20) + (128 << 10) + 4096);

    prep_kernel<<<(GG * DD) / 256, 256, 0, stream>>>(wih, whh, bih, bhh, wih_h, whh_h, bsum);
    gemm_gx<<<(BT / BM) * (GG / BN), 256, 0, stream>>>(x, wih_h, bsum, gx);

    float* hn = out + (size_t)BB * TT * HH;
    float* cn = hn + BB * HH;
    lstm_rec<<<BB, 512, 0, stream>>>(gx, whh_h, out, hn, cn);
}